// Round 9
// baseline (285.997 us; speedup 1.0000x reference)
//
#include <hip/hip_runtime.h>
#include <hip/hip_cooperative_groups.h>
#include <math.h>

namespace cg = cooperative_groups;

#define HH 64
#define WW 64
#define CIN 256
#define COUT 256
#define KKT 9
#define HWSZ 4096
#define VP 260                 // V/row tile pitch in shorts
#define TP 258                 // prep transpose pitch in shorts

typedef __bf16  v8bf    __attribute__((ext_vector_type(8)));
typedef float   v4f     __attribute__((ext_vector_type(4)));
typedef short   short8  __attribute__((ext_vector_type(8)));
typedef unsigned short ushort4v __attribute__((ext_vector_type(4)));
typedef int     int4v   __attribute__((ext_vector_type(4)));
typedef float   float4v __attribute__((ext_vector_type(4)));

__device__ inline unsigned short f2bf(float f) {   // RNE
    union { float f; unsigned u; } uf; uf.f = f;
    unsigned r = uf.u + 0x7fff + ((uf.u >> 16) & 1);
    return (unsigned short)(r >> 16);
}
__device__ inline float bf2f(unsigned short u) {
    union { unsigned u; float f; } uf; uf.u = ((unsigned)u) << 16;
    return uf.f;
}

// ---------------------------------------------------------------------------
// One cooperative kernel, 512 blocks x 512 thr (2 blocks/CU co-resident).
// Phase 1: prep (x->x_t transpose; w->wprep; w_off->woffp)   grid.sync()
// Phase 2: offset conv MFMA -> om                             grid.sync()
// Phase 3: fused bilinear sample + main MFMA GEMM -> out
// Block mapping identical in all phases: b=id>>7, h=(id&7)*8+((id>>4)&7),
// p0=((id>>3)&1)*32  -> XCD keeps an h-band L2-warm across phases.
// ---------------------------------------------------------------------------
__global__ __launch_bounds__(512, 4) void k_fused(
        const float* __restrict__ x, const float* __restrict__ w,
        const float* __restrict__ w_off, const float* __restrict__ b_off,
        unsigned short* __restrict__ x_t, unsigned short* __restrict__ wprep,
        unsigned short* __restrict__ woffp, float* __restrict__ om,
        float* __restrict__ out) {
    cg::grid_group grid = cg::this_grid();

    __shared__ union {
        unsigned short t[64 * TP];                          // 33.0 KB (P1 x)
        float w[2304];                                      //  9.2 KB (P1 w)
        struct { unsigned short row[3 * 34 * VP];           // 53.0 KB
                 float red[4][32][33]; } p2;                // +16.9 = 69.9 KB
        struct { int4v base[KKT][32]; float4v wt[KKT][32];  //  9.2 KB
                 unsigned short v[32 * VP]; } p3;           // +16.6 = 25.9 KB
    } s;

    const int id    = blockIdx.x;
    const int g     = id & 7;
    const int phalf = (id >> 3) & 1;
    const int hi    = (id >> 4) & 7;
    const int b     = id >> 7;
    const int h     = g * 8 + hi;
    const int p0    = phalf * 32;
    const int tid   = threadIdx.x;
    const int lane  = tid & 63;
    const int m16   = lane & 15;
    const int quad  = lane >> 4;

    // ================= Phase 1: prep ======================================
    if (phalf == 0) {
        // x[b][c][h][:] fp32 -> x_t[b][h][:][c] bf16 via LDS transpose
#pragma unroll
        for (int i = 0; i < 8; i++) {
            int idx = i * 512 + tid;   // 0..4095
            int c   = idx >> 4;
            int q   = idx & 15;
            float4 v = *(const float4*)&x[(((size_t)b * CIN + c) * HH + h) * WW + q * 4];
            s.t[(q * 4 + 0) * TP + c] = f2bf(v.x);
            s.t[(q * 4 + 1) * TP + c] = f2bf(v.y);
            s.t[(q * 4 + 2) * TP + c] = f2bf(v.z);
            s.t[(q * 4 + 3) * TP + c] = f2bf(v.w);
        }
        __syncthreads();
#pragma unroll
        for (int i = 0; i < 4; i++) {
            int idx = i * 512 + tid;   // 0..2047
            int px  = idx >> 5;
            int c8  = idx & 31;
            *(short8*)&x_t[(((size_t)(b * 64 + h)) * 64 + px) * CIN + c8 * 8] =
                *(short8*)&s.t[px * TP + c8 * 8];
        }
    } else {
        int o = (b << 6) | (hi << 3) | g;    // 0..255
        for (int i = tid; i < 2304; i += 512) s.w[i] = w[(size_t)o * 2304 + i];
        __syncthreads();
        for (int u = tid; u < 576; u += 512) {
            int t  = u >> 3;
            int kq = u & 7;
            unsigned short v[4];
#pragma unroll
            for (int j = 0; j < 4; j++) {
                int kp = t * 32 + kq * 4 + j;
                int kk = kp >> 8;
                int c  = kp & 255;
                v[j] = f2bf(s.w[c * 9 + kk]);
            }
            *(ushort4v*)&wprep[((size_t)(t * 256 + o)) * 32 + kq * 4] = *(ushort4v*)v;
        }
        if (o < 72) {
            int t = o;
            for (int i = tid; i < 1024; i += 512) {
                int och = i >> 5;
                int ki  = i & 31;
                int kp  = t * 32 + ki;
                int kk  = kp >> 8;
                int c   = kp & 255;
                float v = (och < 27) ? w_off[((size_t)och * 256 + c) * 9 + kk] : 0.f;
                woffp[(size_t)t * 1024 + i] = f2bf(v);
            }
        }
    }
    grid.sync();

    const unsigned short* xb = x_t + (size_t)b * HWSZ * CIN;

    // ================= Phase 2: offset conv MFMA -> om ====================
    {
        int wv  = tid >> 6;            // 0..7
        int ks  = wv >> 1;             // 4-way K split
        int ntw = wv & 1;              // px 16-tile

        for (int u = tid; u < 3 * 1088; u += 512) {    // short8 units
            int row = u / 1088;
            int rem = u - row * 1088;
            int px  = rem >> 5;
            int c8  = (rem & 31) * 8;
            int y   = h + row - 1;
            int xg  = p0 + px - 1;
            short8 val = (short8)0;
            if ((unsigned)y < HH && (unsigned)xg < WW)
                val = *(const short8*)(xb + ((size_t)y * WW + xg) * CIN + c8);
            *(short8*)&s.p2.row[(row * 34 + px) * VP + c8] = val;
        }
        __syncthreads();

        v4f aco[2];
        aco[0] = (v4f)(0.f);
        aco[1] = (v4f)(0.f);
#pragma unroll 3
        for (int j = 0; j < 18; j++) {
            int t  = j * 4 + ks;
            int kk = t >> 3;
            int ch = t & 7;
            int ky = kk / 3;
            int kx = kk - 3 * ky;
            const unsigned short* wp = woffp + (size_t)t * 1024;
            short8 af0 = *(const short8*)(wp + m16 * 32 + quad * 8);
            short8 af1 = *(const short8*)(wp + (16 + m16) * 32 + quad * 8);
            short8 bfr = *(const short8*)
                &s.p2.row[(ky * 34 + ntw * 16 + m16 + kx) * VP + ch * 32 + quad * 8];
            aco[0] = __builtin_amdgcn_mfma_f32_16x16x32_bf16(
                __builtin_bit_cast(v8bf, af0), __builtin_bit_cast(v8bf, bfr), aco[0], 0, 0, 0);
            aco[1] = __builtin_amdgcn_mfma_f32_16x16x32_bf16(
                __builtin_bit_cast(v8bf, af1), __builtin_bit_cast(v8bf, bfr), aco[1], 0, 0, 0);
        }
#pragma unroll
        for (int mt = 0; mt < 2; mt++)
#pragma unroll
            for (int r = 0; r < 4; r++)
                s.p2.red[ks][mt * 16 + quad * 4 + r][ntw * 16 + m16] = aco[mt][r];
        __syncthreads();

        for (int i2 = tid; i2 < 27 * 32; i2 += 512) {
            int och = i2 >> 5;
            int px  = i2 & 31;
            float sm = s.p2.red[0][och][px] + s.p2.red[1][och][px]
                     + s.p2.red[2][och][px] + s.p2.red[3][och][px] + b_off[och];
            om[((size_t)b * 27 + och) * HWSZ + h * WW + p0 + px] = sm;
        }
    }
    grid.sync();

    // ================= Phase 3: fused sample + main GEMM (R6 k_main) ======
    {
        int oct = tid >> 6;            // wave 0..7: o in [oct*32, +32)

        const float* omb = om + (size_t)b * 27 * HWSZ + h * WW;
        for (int i = tid; i < KKT * 32; i += 512) {
            int kk = i >> 5;
            int pl = i & 31;
            int p  = p0 + pl;
            float offy = omb[(size_t)(2 * kk)     * HWSZ + p];
            float offx = omb[(size_t)(2 * kk + 1) * HWSZ + p];
            float mv   = omb[(size_t)(18 + kk)    * HWSZ + p];
            int ky = kk / 3, kx = kk - 3 * (kk / 3);
            float py = (float)(h - 1 + ky) + offy;
            float px = (float)(p - 1 + kx) + offx;
            float y0f = floorf(py);
            float x0f = floorf(px);
            float ly = py - y0f, lx = px - x0f;
            int y0 = (int)y0f, x0 = (int)x0f;
            float m = 1.f / (1.f + __expf(-mv));
            bool yv0 = (unsigned)y0       < HH;
            bool yv1 = (unsigned)(y0 + 1) < HH;
            bool xv0 = (unsigned)x0       < WW;
            bool xv1 = (unsigned)(x0 + 1) < WW;
            int y0c = min(max(y0, 0), HH - 1);
            int y1c = min(max(y0 + 1, 0), HH - 1);
            int x0c = min(max(x0, 0), WW - 1);
            int x1c = min(max(x0 + 1, 0), WW - 1);
            int4v bse;
            bse.x = (y0c * WW + x0c) * CIN;
            bse.y = (y0c * WW + x1c) * CIN;
            bse.z = (y1c * WW + x0c) * CIN;
            bse.w = (y1c * WW + x1c) * CIN;
            s.p3.base[kk][pl] = bse;
            float4v wt;
            wt.x = (yv0 && xv0) ? (1.f - ly) * (1.f - lx) * m : 0.f;
            wt.y = (yv0 && xv1) ? (1.f - ly) * lx         * m : 0.f;
            wt.z = (yv1 && xv0) ? ly * (1.f - lx)         * m : 0.f;
            wt.w = (yv1 && xv1) ? ly * lx                 * m : 0.f;
            s.p3.wt[kk][pl] = wt;
        }
        __syncthreads();

        v4f acc[2][2];
#pragma unroll
        for (int mt = 0; mt < 2; mt++)
#pragma unroll
            for (int nt = 0; nt < 2; nt++) acc[mt][nt] = (v4f)(0.f);

        const unsigned short* xc = xb + lane * 4;

        for (int kk = 0; kk < KKT; kk++) {
            // stage V_kk[32px][256ch]: wave oct -> px oct*4..+3, lanes = ch
#pragma unroll
            for (int i = 0; i < 4; i++) {
                int pl = oct * 4 + i;
                int4v   bp = s.p3.base[kk][pl];   // wave-uniform broadcast
                float4v wt = s.p3.wt[kk][pl];
                ushort4v t0 = *(const ushort4v*)(xc + bp.x);
                ushort4v t1 = *(const ushort4v*)(xc + bp.y);
                ushort4v t2 = *(const ushort4v*)(xc + bp.z);
                ushort4v t3 = *(const ushort4v*)(xc + bp.w);
                unsigned short vv[4];
#pragma unroll
                for (int j = 0; j < 4; j++) {
                    float val = wt.x * bf2f(t0[j]) + wt.y * bf2f(t1[j])
                              + wt.z * bf2f(t2[j]) + wt.w * bf2f(t3[j]);
                    vv[j] = f2bf(val);
                }
                *(ushort4v*)&s.p3.v[pl * VP + lane * 4] = *(ushort4v*)vv;
            }
            __syncthreads();

            // MFMA: 8 chunks x (2 m-tiles x 2 n-tiles)
#pragma unroll 2
            for (int ch = 0; ch < 8; ch++) {
                int t = kk * 8 + ch;
                const unsigned short* wp = wprep + ((size_t)t * 256 + oct * 32) * 32;
                short8 af0 = *(const short8*)(wp + m16 * 32 + quad * 8);
                short8 af1 = *(const short8*)(wp + (16 + m16) * 32 + quad * 8);
                short8 bfr[2];
#pragma unroll
                for (int nt = 0; nt < 2; nt++)
                    bfr[nt] = *(const short8*)&s.p3.v[(nt * 16 + m16) * VP + ch * 32 + quad * 8];
#pragma unroll
                for (int nt = 0; nt < 2; nt++) {
                    acc[0][nt] = __builtin_amdgcn_mfma_f32_16x16x32_bf16(
                        __builtin_bit_cast(v8bf, af0), __builtin_bit_cast(v8bf, bfr[nt]),
                        acc[0][nt], 0, 0, 0);
                    acc[1][nt] = __builtin_amdgcn_mfma_f32_16x16x32_bf16(
                        __builtin_bit_cast(v8bf, af1), __builtin_bit_cast(v8bf, bfr[nt]),
                        acc[1][nt], 0, 0, 0);
                }
            }
            __syncthreads();
        }

        float* ob = out + ((size_t)b * COUT) * HWSZ + h * WW + p0;
#pragma unroll
        for (int mt = 0; mt < 2; mt++)
#pragma unroll
            for (int nt = 0; nt < 2; nt++)
#pragma unroll
                for (int r = 0; r < 4; r++) {
                    int o = oct * 32 + mt * 16 + quad * 4 + r;
                    ob[(size_t)o * HWSZ + nt * 16 + m16] = acc[mt][nt][r];
                }
    }
}

extern "C" void kernel_launch(void* const* d_in, const int* in_sizes, int n_in,
                              void* d_out, int out_size, void* d_ws, size_t ws_size,
                              hipStream_t stream) {
    const float* x     = (const float*)d_in[0];
    const float* w_off = (const float*)d_in[1];
    const float* b_off = (const float*)d_in[2];
    const float* w     = (const float*)d_in[3];
    float* out = (float*)d_out;

    float* om = (float*)d_ws;                                // 442368 f32
    unsigned short* x_t   = (unsigned short*)(om + 442368);  // 4*4096*256 bf16
    unsigned short* wprep = x_t + (size_t)4 * HWSZ * CIN;    // 589824 bf16
    unsigned short* woffp = wprep + 589824;                  // 73728 bf16

    void* args[] = {(void*)&x, (void*)&w, (void*)&w_off, (void*)&b_off,
                    (void*)&x_t, (void*)&wprep, (void*)&woffp, (void*)&om,
                    (void*)&out};
    hipLaunchCooperativeKernel((void*)k_fused, dim3(512), dim3(512), args, 0, stream);
}

// Round 10
// 172.391 us; speedup vs baseline: 1.6590x; 1.6590x over previous
//
#include <hip/hip_runtime.h>
#include <math.h>

#define HH 64
#define WW 64
#define CIN 256
#define COUT 256
#define KKT 9
#define HWSZ 4096
#define VP 260                 // LDS row pitch in shorts
#define TP 258                 // prep transpose row pitch in shorts

typedef __bf16  v8bf   __attribute__((ext_vector_type(8)));
typedef float   v4f    __attribute__((ext_vector_type(4)));
typedef short   short8 __attribute__((ext_vector_type(8)));
typedef unsigned short ushort4v __attribute__((ext_vector_type(4)));

__device__ inline unsigned short f2bf(float f) {   // RNE
    union { float f; unsigned u; } uf; uf.f = f;
    unsigned r = uf.u + 0x7fff + ((uf.u >> 16) & 1);
    return (unsigned short)(r >> 16);
}
__device__ inline float bf2f(unsigned short u) {
    union { unsigned u; float f; } uf; uf.u = ((unsigned)u) << 16;
    return uf.f;
}

// ---------------------------------------------------------------------------
// Prep. Blocks 0..255: x -> x_t via float4 coalesced loads + LDS transpose.
// Blocks 256..511: w -> wprep. Blocks 512..583: w_off -> woffp.
// ---------------------------------------------------------------------------
__global__ __launch_bounds__(256) void k_prep(const float* __restrict__ x,
                                              const float* __restrict__ w,
                                              const float* __restrict__ w_off,
                                              unsigned short* __restrict__ x_t,
                                              unsigned short* __restrict__ wprep,
                                              unsigned short* __restrict__ woffp) {
    __shared__ union {
        unsigned short t[64 * TP];     // 33 KB transpose buffer
        float w[2304];
    } s;
    int id  = blockIdx.x;
    int tid = threadIdx.x;
    if (id < 256) {
        int b = id >> 6;
        int h = id & 63;
        // pass 1: coalesced float4 reads of x rows, scatter to LDS[px][c]
#pragma unroll
        for (int i = 0; i < 16; i++) {
            int idx = i * 256 + tid;   // 0..4095
            int c   = idx >> 4;        // 0..255
            int q   = idx & 15;        // float4 index within the row
            float4 v = *(const float4*)&x[(((size_t)b * CIN + c) * HH + h) * WW + q * 4];
            s.t[(q * 4 + 0) * TP + c] = f2bf(v.x);
            s.t[(q * 4 + 1) * TP + c] = f2bf(v.y);
            s.t[(q * 4 + 2) * TP + c] = f2bf(v.z);
            s.t[(q * 4 + 3) * TP + c] = f2bf(v.w);
        }
        __syncthreads();
        // pass 2: contiguous 16B stores, fully coalesced
#pragma unroll
        for (int i = 0; i < 8; i++) {
            int idx = i * 256 + tid;   // 0..2047
            int px  = idx >> 5;
            int c8  = idx & 31;
            *(short8*)&x_t[(((size_t)id) * 64 + px) * CIN + c8 * 8] =
                *(short8*)&s.t[px * TP + c8 * 8];
        }
    } else if (id < 512) {
        int o = id - 256;
        for (int i = tid; i < 2304; i += 256) s.w[i] = w[(size_t)o * 2304 + i];
        __syncthreads();
        for (int u = tid; u < 576; u += 256) {
            int t  = u >> 3;
            int kq = u & 7;
            unsigned short v[4];
#pragma unroll
            for (int j = 0; j < 4; j++) {
                int kp = t * 32 + kq * 4 + j;
                int kk = kp >> 8;
                int c  = kp & 255;
                v[j] = f2bf(s.w[c * 9 + kk]);
            }
            *(ushort4v*)&wprep[((size_t)(t * 256 + o)) * 32 + kq * 4] = *(ushort4v*)v;
        }
    } else {
        int t = id - 512;              // 0..71
#pragma unroll
        for (int i = 0; i < 4; i++) {
            int idx = i * 256 + tid;
            int och = idx >> 5;
            int ki  = idx & 31;
            int kp  = t * 32 + ki;
            int kk  = kp >> 8;
            int c   = kp & 255;
            float v = (och < 27) ? w_off[((size_t)och * 256 + c) * 9 + kk] : 0.f;
            woffp[(size_t)t * 1024 + idx] = f2bf(v);
        }
    }
}

// ---------------------------------------------------------------------------
// Offset conv MFMA (R6 version, unchanged). Grid 512: block = (b, h, px-half).
// 256 thr, 4 waves, K split over wave-pairs, LDS reduce.
// ---------------------------------------------------------------------------
__global__ __launch_bounds__(256) void k_off_mfma(const unsigned short* __restrict__ x_t,
                                                  const unsigned short* __restrict__ woffp,
                                                  const float* __restrict__ b_off,
                                                  float* __restrict__ om) {
    int id    = blockIdx.x;
    int g     = id & 7;
    int phalf = (id >> 3) & 1;
    int hi    = (id >> 4) & 7;
    int b     = id >> 7;
    int h     = g * 8 + hi;
    int p0    = phalf * 32;
    int tid  = threadIdx.x;
    int lane = tid & 63;
    int wv   = tid >> 6;
    int g2   = wv >> 1;
    int ntw  = wv & 1;
    int m16  = lane & 15;
    int quad = lane >> 4;

    __shared__ unsigned short s_row[3 * 34 * VP];
    __shared__ float s_red[2][32][33];

    const unsigned short* xb = x_t + (size_t)b * HWSZ * CIN;

    for (int u = tid; u < 3 * 1088; u += 256) {
        int row = u / 1088;
        int rem = u - row * 1088;
        int px  = rem >> 5;
        int c8  = (rem & 31) * 8;
        int y   = h + row - 1;
        int xg  = p0 + px - 1;
        short8 val = (short8)0;
        if ((unsigned)y < HH && (unsigned)xg < WW)
            val = *(const short8*)(xb + ((size_t)y * WW + xg) * CIN + c8);
        *(short8*)&s_row[(row * 34 + px) * VP + c8] = val;
    }
    __syncthreads();

    v4f acc[2];
    acc[0] = (v4f)(0.f);
    acc[1] = (v4f)(0.f);

#pragma unroll
    for (int ky = 0; ky < 3; ky++) {
#pragma unroll
        for (int kx = 0; kx < 3; kx++) {
#pragma unroll
            for (int c2 = 0; c2 < 4; c2++) {
                int ch = c2 * 2 + g2;
                int t  = (ky * 3 + kx) * 8 + ch;
                const unsigned short* wp = woffp + (size_t)t * 1024;
                short8 af0 = *(const short8*)(wp + m16 * 32 + quad * 8);
                short8 af1 = *(const short8*)(wp + (16 + m16) * 32 + quad * 8);
                short8 bfr = *(const short8*)
                    &s_row[(ky * 34 + ntw * 16 + m16 + kx) * VP + ch * 32 + quad * 8];
                acc[0] = __builtin_amdgcn_mfma_f32_16x16x32_bf16(
                    __builtin_bit_cast(v8bf, af0), __builtin_bit_cast(v8bf, bfr), acc[0], 0, 0, 0);
                acc[1] = __builtin_amdgcn_mfma_f32_16x16x32_bf16(
                    __builtin_bit_cast(v8bf, af1), __builtin_bit_cast(v8bf, bfr), acc[1], 0, 0, 0);
            }
        }
    }

#pragma unroll
    for (int mt = 0; mt < 2; mt++)
#pragma unroll
        for (int r = 0; r < 4; r++)
            s_red[g2][mt * 16 + quad * 4 + r][ntw * 16 + m16] = acc[mt][r];
    __syncthreads();

    for (int i2 = tid; i2 < 27 * 32; i2 += 256) {
        int och = i2 >> 5;
        int px  = i2 & 31;
        float s = s_red[0][och][px] + s_red[1][och][px] + b_off[och];
        om[((size_t)b * 27 + och) * HWSZ + h * WW + p0 + px] = s;
    }
}

// ---------------------------------------------------------------------------
// Main fused sample+GEMM — R6 structure + double-buffered s_v (ONE barrier
// per kk). Grid 512 = (b, h, px-half). 512 thr (8 waves). Tile 256o x 32px.
// ---------------------------------------------------------------------------
__global__ __launch_bounds__(512, 4) void k_main(const unsigned short* __restrict__ x_t,
                                                 const float* __restrict__ om,
                                                 const unsigned short* __restrict__ wprep,
                                                 float* __restrict__ out) {
    int id    = blockIdx.x;
    int g     = id & 7;
    int phalf = (id >> 3) & 1;
    int hi    = (id >> 4) & 7;
    int b     = id >> 7;
    int h     = g * 8 + hi;
    int p0    = phalf * 32;
    int tid  = threadIdx.x;
    int lane = tid & 63;
    int oct  = tid >> 6;               // wave 0..7: o in [oct*32, +32)
    int m16  = lane & 15;
    int quad = lane >> 4;

    __shared__ int4   s_base[KKT][32];
    __shared__ float4 s_wt  [KKT][32];
    __shared__ unsigned short s_v[2][32 * VP];   // 33.3 KB double buffer

    // ---- Phase A: sampling params for 9 kk x 32 px ----
    const float* omb = om + (size_t)b * 27 * HWSZ + h * WW;
    for (int i = tid; i < KKT * 32; i += 512) {
        int kk = i >> 5;
        int pl = i & 31;
        int p  = p0 + pl;
        float offy = omb[(size_t)(2 * kk)     * HWSZ + p];
        float offx = omb[(size_t)(2 * kk + 1) * HWSZ + p];
        float mv   = omb[(size_t)(18 + kk)    * HWSZ + p];
        int ky = kk / 3, kx = kk - 3 * (kk / 3);
        float py = (float)(h - 1 + ky) + offy;
        float px = (float)(p - 1 + kx) + offx;
        float y0f = floorf(py);
        float x0f = floorf(px);
        float ly = py - y0f, lx = px - x0f;
        int y0 = (int)y0f, x0 = (int)x0f;
        float m = 1.f / (1.f + __expf(-mv));
        bool yv0 = (unsigned)y0       < HH;
        bool yv1 = (unsigned)(y0 + 1) < HH;
        bool xv0 = (unsigned)x0       < WW;
        bool xv1 = (unsigned)(x0 + 1) < WW;
        int y0c = min(max(y0, 0), HH - 1);
        int y1c = min(max(y0 + 1, 0), HH - 1);
        int x0c = min(max(x0, 0), WW - 1);
        int x1c = min(max(x0 + 1, 0), WW - 1);
        s_base[kk][pl] = make_int4((y0c * WW + x0c) * CIN, (y0c * WW + x1c) * CIN,
                                   (y1c * WW + x0c) * CIN, (y1c * WW + x1c) * CIN);
        s_wt[kk][pl] = make_float4(
            (yv0 && xv0) ? (1.f - ly) * (1.f - lx) * m : 0.f,
            (yv0 && xv1) ? (1.f - ly) * lx         * m : 0.f,
            (yv1 && xv0) ? ly * (1.f - lx)         * m : 0.f,
            (yv1 && xv1) ? ly * lx                 * m : 0.f);
    }
    __syncthreads();

    v4f acc[2][2];
#pragma unroll
    for (int mt = 0; mt < 2; mt++)
#pragma unroll
        for (int nt = 0; nt < 2; nt++) acc[mt][nt] = (v4f)(0.f);

    const unsigned short* xb = x_t + (size_t)b * HWSZ * CIN;
    const unsigned short* xc = xb + lane * 4;

    for (int kk = 0; kk < KKT; kk++) {
        unsigned short* vbuf = s_v[kk & 1];

        // ---- stage V_kk: wave oct -> px oct*4..+3, lanes = channels ----
#pragma unroll
        for (int i = 0; i < 4; i++) {
            int pl = oct * 4 + i;
            int4   bp = s_base[kk][pl];    // wave-uniform broadcast
            float4 wt = s_wt[kk][pl];
            ushort4v t0 = *(const ushort4v*)(xc + bp.x);
            ushort4v t1 = *(const ushort4v*)(xc + bp.y);
            ushort4v t2 = *(const ushort4v*)(xc + bp.z);
            ushort4v t3 = *(const ushort4v*)(xc + bp.w);
            unsigned short vv[4];
#pragma unroll
            for (int j = 0; j < 4; j++) {
                float val = wt.x * bf2f(t0[j]) + wt.y * bf2f(t1[j])
                          + wt.z * bf2f(t2[j]) + wt.w * bf2f(t3[j]);
                vv[j] = f2bf(val);
            }
            *(ushort4v*)&vbuf[pl * VP + lane * 4] = *(ushort4v*)vv;
        }
        __syncthreads();

        // ---- 8 K-chunks of MFMA for this kk ----
#pragma unroll 2
        for (int ch = 0; ch < 8; ch++) {
            int t = kk * 8 + ch;
            const unsigned short* wp = wprep + ((size_t)t * 256 + oct * 32) * 32;
            short8 af0 = *(const short8*)(wp + m16 * 32 + quad * 8);
            short8 af1 = *(const short8*)(wp + (16 + m16) * 32 + quad * 8);
            short8 bfr[2];
#pragma unroll
            for (int nt = 0; nt < 2; nt++)
                bfr[nt] = *(const short8*)&vbuf[(nt * 16 + m16) * VP + ch * 32 + quad * 8];
#pragma unroll
            for (int nt = 0; nt < 2; nt++) {
                acc[0][nt] = __builtin_amdgcn_mfma_f32_16x16x32_bf16(
                    __builtin_bit_cast(v8bf, af0), __builtin_bit_cast(v8bf, bfr[nt]),
                    acc[0][nt], 0, 0, 0);
                acc[1][nt] = __builtin_amdgcn_mfma_f32_16x16x32_bf16(
                    __builtin_bit_cast(v8bf, af1), __builtin_bit_cast(v8bf, bfr[nt]),
                    acc[1][nt], 0, 0, 0);
            }
        }
        // no trailing barrier: next kk writes the other V buffer; each wave's
        // ds_reads drain (lgkmcnt) before it can pass the next __syncthreads.
    }

    // ---- epilogue ----
    float* ob = out + ((size_t)b * COUT) * HWSZ + h * WW + p0;
#pragma unroll
    for (int mt = 0; mt < 2; mt++)
#pragma unroll
        for (int nt = 0; nt < 2; nt++)
#pragma unroll
            for (int r = 0; r < 4; r++) {
                int o = oct * 32 + mt * 16 + quad * 4 + r;
                ob[(size_t)o * HWSZ + nt * 16 + m16] = acc[mt][nt][r];
            }
}

extern "C" void kernel_launch(void* const* d_in, const int* in_sizes, int n_in,
                              void* d_out, int out_size, void* d_ws, size_t ws_size,
                              hipStream_t stream) {
    const float* x     = (const float*)d_in[0];
    const float* w_off = (const float*)d_in[1];
    const float* b_off = (const float*)d_in[2];
    const float* w     = (const float*)d_in[3];
    float* out = (float*)d_out;

    float* om = (float*)d_ws;                                // 442368 f32
    unsigned short* x_t   = (unsigned short*)(om + 442368);  // 4*4096*256 bf16
    unsigned short* wprep = x_t + (size_t)4 * HWSZ * CIN;    // 589824 bf16
    unsigned short* woffp = wprep + 589824;                  // 73728 bf16

    hipLaunchKernelGGL(k_prep,     dim3(584), dim3(256), 0, stream, x, w, w_off, x_t, wprep, woffp);
    hipLaunchKernelGGL(k_off_mfma, dim3(512), dim3(256), 0, stream, x_t, woffp, b_off, om);
    hipLaunchKernelGGL(k_main,     dim3(512), dim3(512), 0, stream, x_t, om, wprep, out);
}

// Round 11
// 146.868 us; speedup vs baseline: 1.9473x; 1.1738x over previous
//
#include <hip/hip_runtime.h>
#include <math.h>

#define HH 64
#define WW 64
#define CIN 256
#define COUT 256
#define KKT 9
#define HWSZ 4096
#define VP 260                 // LDS row pitch in shorts
#define TP 258                 // prep transpose row pitch in shorts

typedef __bf16  v8bf   __attribute__((ext_vector_type(8)));
typedef float   v4f    __attribute__((ext_vector_type(4)));
typedef short   short8 __attribute__((ext_vector_type(8)));
typedef unsigned short ushort4v __attribute__((ext_vector_type(4)));

__device__ inline unsigned short f2bf(float f) {   // RNE
    union { float f; unsigned u; } uf; uf.f = f;
    unsigned r = uf.u + 0x7fff + ((uf.u >> 16) & 1);
    return (unsigned short)(r >> 16);
}
__device__ inline float bf2f(unsigned short u) {
    union { unsigned u; float f; } uf; uf.u = ((unsigned)u) << 16;
    return uf.f;
}

// ---------------------------------------------------------------------------
// Prep. Blocks 0..255: x -> x_t via float4 coalesced loads + LDS transpose.
// Blocks 256..511: w -> wprep. Blocks 512..583: w_off -> woffp.
// ---------------------------------------------------------------------------
__global__ __launch_bounds__(256) void k_prep(const float* __restrict__ x,
                                              const float* __restrict__ w,
                                              const float* __restrict__ w_off,
                                              unsigned short* __restrict__ x_t,
                                              unsigned short* __restrict__ wprep,
                                              unsigned short* __restrict__ woffp) {
    __shared__ union {
        unsigned short t[64 * TP];     // 33 KB transpose buffer
        float w[2304];
    } s;
    int id  = blockIdx.x;
    int tid = threadIdx.x;
    if (id < 256) {
        int b = id >> 6;
        int h = id & 63;
#pragma unroll
        for (int i = 0; i < 16; i++) {
            int idx = i * 256 + tid;   // 0..4095
            int c   = idx >> 4;
            int q   = idx & 15;
            float4 v = *(const float4*)&x[(((size_t)b * CIN + c) * HH + h) * WW + q * 4];
            s.t[(q * 4 + 0) * TP + c] = f2bf(v.x);
            s.t[(q * 4 + 1) * TP + c] = f2bf(v.y);
            s.t[(q * 4 + 2) * TP + c] = f2bf(v.z);
            s.t[(q * 4 + 3) * TP + c] = f2bf(v.w);
        }
        __syncthreads();
#pragma unroll
        for (int i = 0; i < 8; i++) {
            int idx = i * 256 + tid;   // 0..2047
            int px  = idx >> 5;
            int c8  = idx & 31;
            *(short8*)&x_t[(((size_t)id) * 64 + px) * CIN + c8 * 8] =
                *(short8*)&s.t[px * TP + c8 * 8];
        }
    } else if (id < 512) {
        int o = id - 256;
        for (int i = tid; i < 2304; i += 256) s.w[i] = w[(size_t)o * 2304 + i];
        __syncthreads();
        for (int u = tid; u < 576; u += 256) {
            int t  = u >> 3;
            int kq = u & 7;
            unsigned short v[4];
#pragma unroll
            for (int j = 0; j < 4; j++) {
                int kp = t * 32 + kq * 4 + j;
                int kk = kp >> 8;
                int c  = kp & 255;
                v[j] = f2bf(s.w[c * 9 + kk]);
            }
            *(ushort4v*)&wprep[((size_t)(t * 256 + o)) * 32 + kq * 4] = *(ushort4v*)v;
        }
    } else {
        int t = id - 512;              // 0..71
#pragma unroll
        for (int i = 0; i < 4; i++) {
            int idx = i * 256 + tid;
            int och = idx >> 5;
            int ki  = idx & 31;
            int kp  = t * 32 + ki;
            int kk  = kp >> 8;
            int c   = kp & 255;
            float v = (och < 27) ? w_off[((size_t)och * 256 + c) * 9 + kk] : 0.f;
            woffp[(size_t)t * 1024 + idx] = f2bf(v);
        }
    }
}

// ---------------------------------------------------------------------------
// Offset conv MFMA (R6 version, unchanged). Grid 512: block = (b, h, px-half).
// 256 thr, 4 waves, K split over wave-pairs, LDS reduce.
// ---------------------------------------------------------------------------
__global__ __launch_bounds__(256) void k_off_mfma(const unsigned short* __restrict__ x_t,
                                                  const unsigned short* __restrict__ woffp,
                                                  const float* __restrict__ b_off,
                                                  float* __restrict__ om) {
    int id    = blockIdx.x;
    int g     = id & 7;
    int phalf = (id >> 3) & 1;
    int hi    = (id >> 4) & 7;
    int b     = id >> 7;
    int h     = g * 8 + hi;
    int p0    = phalf * 32;
    int tid  = threadIdx.x;
    int lane = tid & 63;
    int wv   = tid >> 6;
    int g2   = wv >> 1;
    int ntw  = wv & 1;
    int m16  = lane & 15;
    int quad = lane >> 4;

    __shared__ unsigned short s_row[3 * 34 * VP];
    __shared__ float s_red[2][32][33];

    const unsigned short* xb = x_t + (size_t)b * HWSZ * CIN;

    for (int u = tid; u < 3 * 1088; u += 256) {
        int row = u / 1088;
        int rem = u - row * 1088;
        int px  = rem >> 5;
        int c8  = (rem & 31) * 8;
        int y   = h + row - 1;
        int xg  = p0 + px - 1;
        short8 val = (short8)0;
        if ((unsigned)y < HH && (unsigned)xg < WW)
            val = *(const short8*)(xb + ((size_t)y * WW + xg) * CIN + c8);
        *(short8*)&s_row[(row * 34 + px) * VP + c8] = val;
    }
    __syncthreads();

    v4f acc[2];
    acc[0] = (v4f)(0.f);
    acc[1] = (v4f)(0.f);

#pragma unroll
    for (int ky = 0; ky < 3; ky++) {
#pragma unroll
        for (int kx = 0; kx < 3; kx++) {
#pragma unroll
            for (int c2 = 0; c2 < 4; c2++) {
                int ch = c2 * 2 + g2;
                int t  = (ky * 3 + kx) * 8 + ch;
                const unsigned short* wp = woffp + (size_t)t * 1024;
                short8 af0 = *(const short8*)(wp + m16 * 32 + quad * 8);
                short8 af1 = *(const short8*)(wp + (16 + m16) * 32 + quad * 8);
                short8 bfr = *(const short8*)
                    &s_row[(ky * 34 + ntw * 16 + m16 + kx) * VP + ch * 32 + quad * 8];
                acc[0] = __builtin_amdgcn_mfma_f32_16x16x32_bf16(
                    __builtin_bit_cast(v8bf, af0), __builtin_bit_cast(v8bf, bfr), acc[0], 0, 0, 0);
                acc[1] = __builtin_amdgcn_mfma_f32_16x16x32_bf16(
                    __builtin_bit_cast(v8bf, af1), __builtin_bit_cast(v8bf, bfr), acc[1], 0, 0, 0);
            }
        }
    }

#pragma unroll
    for (int mt = 0; mt < 2; mt++)
#pragma unroll
        for (int r = 0; r < 4; r++)
            s_red[g2][mt * 16 + quad * 4 + r][ntw * 16 + m16] = acc[mt][r];
    __syncthreads();

    for (int i2 = tid; i2 < 27 * 32; i2 += 256) {
        int och = i2 >> 5;
        int px  = i2 & 31;
        float s = s_red[0][och][px] + s_red[1][och][px] + b_off[och];
        om[((size_t)b * 27 + och) * HWSZ + h * WW + p0 + px] = s;
    }
}

// ---------------------------------------------------------------------------
// Main fused sample+GEMM — EXACT R6 structure (2 barriers/kk, static s_v),
// with register batching only:
//   (a) all 16 corner gathers loaded before any convert (1 vmcnt round),
//   (b) the kk's full W set (af[8][2]) loaded BEFORE the barrier, so W L2
//       latency is absorbed by the barrier wait.
// Grid 512 = (b, h, px-half). 512 thr (8 waves). Tile 256o x 32px.
// ---------------------------------------------------------------------------
__global__ __launch_bounds__(512, 4) void k_main(const unsigned short* __restrict__ x_t,
                                                 const float* __restrict__ om,
                                                 const unsigned short* __restrict__ wprep,
                                                 float* __restrict__ out) {
    int id    = blockIdx.x;
    int g     = id & 7;
    int phalf = (id >> 3) & 1;
    int hi    = (id >> 4) & 7;
    int b     = id >> 7;
    int h     = g * 8 + hi;
    int p0    = phalf * 32;
    int tid  = threadIdx.x;
    int lane = tid & 63;
    int oct  = tid >> 6;               // wave 0..7: o in [oct*32, +32)
    int m16  = lane & 15;
    int quad = lane >> 4;

    __shared__ int4   s_base[KKT][32];
    __shared__ float4 s_wt  [KKT][32];
    __shared__ unsigned short s_v[32 * VP];

    // ---- Phase A: sampling params for 9 kk x 32 px ----
    const float* omb = om + (size_t)b * 27 * HWSZ + h * WW;
    for (int i = tid; i < KKT * 32; i += 512) {
        int kk = i >> 5;
        int pl = i & 31;
        int p  = p0 + pl;
        float offy = omb[(size_t)(2 * kk)     * HWSZ + p];
        float offx = omb[(size_t)(2 * kk + 1) * HWSZ + p];
        float mv   = omb[(size_t)(18 + kk)    * HWSZ + p];
        int ky = kk / 3, kx = kk - 3 * (kk / 3);
        float py = (float)(h - 1 + ky) + offy;
        float px = (float)(p - 1 + kx) + offx;
        float y0f = floorf(py);
        float x0f = floorf(px);
        float ly = py - y0f, lx = px - x0f;
        int y0 = (int)y0f, x0 = (int)x0f;
        float m = 1.f / (1.f + __expf(-mv));
        bool yv0 = (unsigned)y0       < HH;
        bool yv1 = (unsigned)(y0 + 1) < HH;
        bool xv0 = (unsigned)x0       < WW;
        bool xv1 = (unsigned)(x0 + 1) < WW;
        int y0c = min(max(y0, 0), HH - 1);
        int y1c = min(max(y0 + 1, 0), HH - 1);
        int x0c = min(max(x0, 0), WW - 1);
        int x1c = min(max(x0 + 1, 0), WW - 1);
        s_base[kk][pl] = make_int4((y0c * WW + x0c) * CIN, (y0c * WW + x1c) * CIN,
                                   (y1c * WW + x0c) * CIN, (y1c * WW + x1c) * CIN);
        s_wt[kk][pl] = make_float4(
            (yv0 && xv0) ? (1.f - ly) * (1.f - lx) * m : 0.f,
            (yv0 && xv1) ? (1.f - ly) * lx         * m : 0.f,
            (yv1 && xv0) ? ly * (1.f - lx)         * m : 0.f,
            (yv1 && xv1) ? ly * lx                 * m : 0.f);
    }
    __syncthreads();

    v4f acc[2][2];
#pragma unroll
    for (int mt = 0; mt < 2; mt++)
#pragma unroll
        for (int nt = 0; nt < 2; nt++) acc[mt][nt] = (v4f)(0.f);

    const unsigned short* xb = x_t + (size_t)b * HWSZ * CIN;
    const unsigned short* xc = xb + lane * 4;

    for (int kk = 0; kk < KKT; kk++) {
        // ---- (a) batch all 16 corner gathers into registers ----
        ushort4v tc[4][4];
#pragma unroll
        for (int i = 0; i < 4; i++) {
            int4 bp = s_base[kk][oct * 4 + i];   // wave-uniform broadcast
            tc[i][0] = *(const ushort4v*)(xc + bp.x);
            tc[i][1] = *(const ushort4v*)(xc + bp.y);
            tc[i][2] = *(const ushort4v*)(xc + bp.z);
            tc[i][3] = *(const ushort4v*)(xc + bp.w);
        }
        // ---- convert + LDS write ----
#pragma unroll
        for (int i = 0; i < 4; i++) {
            int pl = oct * 4 + i;
            float4 wt = s_wt[kk][pl];
            unsigned short vv[4];
#pragma unroll
            for (int j = 0; j < 4; j++) {
                float val = wt.x * bf2f(tc[i][0][j]) + wt.y * bf2f(tc[i][1][j])
                          + wt.z * bf2f(tc[i][2][j]) + wt.w * bf2f(tc[i][3][j]);
                vv[j] = f2bf(val);
            }
            *(ushort4v*)&s_v[pl * VP + lane * 4] = *(ushort4v*)vv;
        }

        // ---- (b) batch the kk's W fragments BEFORE the barrier ----
        short8 af[8][2];
#pragma unroll
        for (int ch = 0; ch < 8; ch++) {
            const unsigned short* wp =
                wprep + ((size_t)(kk * 8 + ch) * 256 + oct * 32) * 32;
            af[ch][0] = *(const short8*)(wp + m16 * 32 + quad * 8);
            af[ch][1] = *(const short8*)(wp + (16 + m16) * 32 + quad * 8);
        }
        __syncthreads();

        // ---- MFMA: 8 chunks from registers + LDS bfr ----
#pragma unroll
        for (int ch = 0; ch < 8; ch++) {
            short8 bfr[2];
#pragma unroll
            for (int nt = 0; nt < 2; nt++)
                bfr[nt] = *(const short8*)&s_v[(nt * 16 + m16) * VP + ch * 32 + quad * 8];
#pragma unroll
            for (int nt = 0; nt < 2; nt++) {
                acc[0][nt] = __builtin_amdgcn_mfma_f32_16x16x32_bf16(
                    __builtin_bit_cast(v8bf, af[ch][0]), __builtin_bit_cast(v8bf, bfr[nt]),
                    acc[0][nt], 0, 0, 0);
                acc[1][nt] = __builtin_amdgcn_mfma_f32_16x16x32_bf16(
                    __builtin_bit_cast(v8bf, af[ch][1]), __builtin_bit_cast(v8bf, bfr[nt]),
                    acc[1][nt], 0, 0, 0);
            }
        }
        __syncthreads();
    }

    // ---- epilogue ----
    float* ob = out + ((size_t)b * COUT) * HWSZ + h * WW + p0;
#pragma unroll
    for (int mt = 0; mt < 2; mt++)
#pragma unroll
        for (int nt = 0; nt < 2; nt++)
#pragma unroll
            for (int r = 0; r < 4; r++) {
                int o = oct * 32 + mt * 16 + quad * 4 + r;
                ob[(size_t)o * HWSZ + nt * 16 + m16] = acc[mt][nt][r];
            }
}

extern "C" void kernel_launch(void* const* d_in, const int* in_sizes, int n_in,
                              void* d_out, int out_size, void* d_ws, size_t ws_size,
                              hipStream_t stream) {
    const float* x     = (const float*)d_in[0];
    const float* w_off = (const float*)d_in[1];
    const float* b_off = (const float*)d_in[2];
    const float* w     = (const float*)d_in[3];
    float* out = (float*)d_out;

    float* om = (float*)d_ws;                                // 442368 f32
    unsigned short* x_t   = (unsigned short*)(om + 442368);  // 4*4096*256 bf16
    unsigned short* wprep = x_t + (size_t)4 * HWSZ * CIN;    // 589824 bf16
    unsigned short* woffp = wprep + 589824;                  // 73728 bf16

    hipLaunchKernelGGL(k_prep,     dim3(584), dim3(256), 0, stream, x, w, w_off, x_t, wprep, woffp);
    hipLaunchKernelGGL(k_off_mfma, dim3(512), dim3(256), 0, stream, x_t, woffp, b_off, om);
    hipLaunchKernelGGL(k_main,     dim3(512), dim3(512), 0, stream, x_t, om, wprep, out);
}